// Round 12
// baseline (113.152 us; speedup 1.0000x reference)
//
#include <hip/hip_runtime.h>

#define B_ 8
#define N_ 256
#define D_ 128
#define E_ 4096

typedef __attribute__((ext_vector_type(8))) short bf16x8;
typedef __attribute__((ext_vector_type(4))) float f32x4;
typedef __attribute__((ext_vector_type(2))) float f32x2;

__device__ inline unsigned int pack2bf(float lo, float hi) {
    unsigned ul = __float_as_uint(lo);
    ul = ul + 0x7FFFu + ((ul >> 16) & 1u);
    unsigned uh = __float_as_uint(hi);
    uh = uh + 0x7FFFu + ((uh >> 16) & 1u);
    return (ul >> 16) | (uh & 0xFFFF0000u);
}

__device__ inline unsigned short f2bf(float f) {
    unsigned u = __float_as_uint(f);
    u = u + 0x7FFFu + ((u >> 16) & 1u);
    return (unsigned short)(u >> 16);
}

// ---------------- ws layout (bytes) ----------------
// 0      : mask   int32 [B*N]     (8192)
// 8192   : jlist  int32 [B*N]     (8192)
// 16384  : jcnt   int32 [B]       (32)
// 16448  : tq     f32 [D]         (512)
// 16960  : dq     f32 [D]         (512)
// 17472  : Wb     bf16 [E][D]     (32768)
// 50240  : Wt     f32 [D][E]      (65536)
// 115776 : s1     f32 [B][D]      (4096)
// 119872 : cdiag  f32 [B][D]      (4096)
// 123968 : part   f32 [B][D][D]   (524288)

__global__ __launch_bounds__(256) void k_prep(const void* __restrict__ edges_raw,
                                              const void* __restrict__ mask_raw,
                                              const float* __restrict__ W,
                                              int* __restrict__ mask,
                                              int* __restrict__ jlist,
                                              int* __restrict__ jcnt,
                                              unsigned short* __restrict__ Wb,
                                              float* __restrict__ Wt,
                                              float* __restrict__ tq,
                                              float* __restrict__ dq) {
    int blk = blockIdx.x, tid = threadIdx.x;
    if (blk >= B_) {
        int idx = (blk - B_) * 256 + tid;      // 0..16639
        if (idx < 16384) {
            float w = W[idx];
            Wb[idx] = f2bf(w);
            int e = idx >> 7, d = idx & 127;
            Wt[d * D_ + e] = w;
        } else if (idx < 16512) tq[idx - 16384] = 0.0f;
        else dq[idx - 16512] = 0.0f;
        return;
    }
    int b = blk;
    __shared__ unsigned char hit[N_];
    __shared__ int flags[2];
    __shared__ int wcnt[4], wbase[4];
    hit[tid] = 0;
    if (tid < 2) flags[tid] = 0;
    __syncthreads();

    const unsigned char* mb = (const unsigned char*)mask_raw;
    int loc_m = 0;
    for (int idx = tid; idx < B_ * N_; idx += 256)
        if ((idx & 3) && mb[idx]) loc_m = 1;
    if (loc_m) flags[0] = 1;
    const int* e32 = (const int*)edges_raw;
    int loc_e = 0;
    for (int idx = tid; idx < 2 * E_; idx += 256)
        if ((idx & 1) && e32[idx]) loc_e = 1;
    if (loc_e) flags[1] = 1;
    __syncthreads();

    int mask_is_u8 = flags[0], e_is_i32 = flags[1];
    const long long* e64 = (const long long*)edges_raw;
    for (int e = tid; e < E_; e += 256) {
        int s, d;
        if (e_is_i32) { s = e32[e]; d = e32[E_ + e]; }
        else          { s = (int)e64[e]; d = (int)e64[E_ + e]; }
        if (d - s == 3) { hit[s] = 1; hit[d] = 1; }
    }
    __syncthreads();

    const int* m32 = (const int*)mask_raw;
    int lane = tid & 63, wid = tid >> 6;
    int raw = mask_is_u8 ? (int)(mb[b * N_ + tid] != 0) : (int)(m32[b * N_ + tid] != 0);
    int m = raw && (hit[tid] == 0);
    mask[b * N_ + tid] = m;
    unsigned long long bal = __ballot(m);
    if (lane == 0) wcnt[wid] = __popcll(bal);
    __syncthreads();
    if (tid == 0) {
        int base = 0;
        for (int w = 0; w < 4; ++w) { wbase[w] = base; base += wcnt[w]; }
        jcnt[b] = base;
    }
    __syncthreads();
    if (m) {
        int pos = wbase[wid] + __popcll(bal & ((1ull << lane) - 1ull));
        jlist[b * N_ + pos] = tid;
    }
}

__global__ __launch_bounds__(128) void k_gram3(const float* __restrict__ x,
                                               const int* __restrict__ jlist,
                                               const int* __restrict__ jcnt,
                                               float* __restrict__ part,
                                               float* __restrict__ s1,
                                               float* __restrict__ cdiag) {
    int d = blockIdx.x, b = blockIdx.y, dp = threadIdx.x;
    int kc = jcnt[b];
    const int* jl = jlist + b * N_;
    const float* xb = x + (size_t)b * N_ * D_;
    float c0 = 0, c1 = 0, q0 = 0, q1 = 0, s0 = 0, s1a = 0;
    int t = 0;
    for (; t + 1 < kc; t += 2) {
        int i0 = jl[t], i1 = jl[t + 1];
        float xd0 = xb[i0 * D_ + d], xp0 = xb[i0 * D_ + dp];
        float xd1 = xb[i1 * D_ + d], xp1 = xb[i1 * D_ + dp];
        c0 += xd0 * xp0; q0 += (xd0 * xd0) * (xp0 * xp0); s0 += xd0;
        c1 += xd1 * xp1; q1 += (xd1 * xd1) * (xp1 * xp1); s1a += xd1;
    }
    if (t < kc) {
        int i0 = jl[t];
        float xd0 = xb[i0 * D_ + d], xp0 = xb[i0 * D_ + dp];
        c0 += xd0 * xp0; q0 += (xd0 * xd0) * (xp0 * xp0); s0 += xd0;
    }
    float c = c0 + c1, q = q0 + q1, sa = s0 + s1a;
    part[((size_t)b * D_ + d) * D_ + dp] = c * c - q;
    if (dp == d) cdiag[b * D_ + d] = c;
    if (dp == 0) s1[b * D_ + d] = sa;
}

__global__ __launch_bounds__(128) void k_mw2(const float* __restrict__ part,
                                             const float* __restrict__ Wt,
                                             const float* __restrict__ s1,
                                             const float* __restrict__ cdiag,
                                             float* __restrict__ tq,
                                             float* __restrict__ dq) {
    __shared__ float Ms[D_];
    __shared__ float svs;
    int d = blockIdx.x, e = threadIdx.x;
    float m = 0.0f;
#pragma unroll
    for (int b = 0; b < B_; ++b) m += part[((size_t)b * D_ + d) * D_ + e];
    Ms[e] = m;
    if (e == 0) {
        float sv = 0.0f;
#pragma unroll
        for (int b = 0; b < B_; ++b) {
            float s = s1[b * D_ + d];
            sv += s * s - cdiag[b * D_ + d];
        }
        svs = sv;
    }
    __syncthreads();
    float y = 0.0f;
#pragma unroll 8
    for (int p = 0; p < D_; ++p) y += Ms[p] * Wt[p * D_ + e];
    float wed = Wt[d * D_ + e];
    atomicAdd(tq + e, wed * y);
    atomicAdd(dq + e, wed * svs);
}

// LDS-free MFMA compute + fused zero-fill; ONE barrier total, nt stores flow freely.
// A-fragments gathered per-lane directly from L2-resident x.
__global__ __launch_bounds__(256) void k_main(const float* __restrict__ x,
                                              const int* __restrict__ mask,
                                              const int* __restrict__ jlist,
                                              const int* __restrict__ jcnt,
                                              const unsigned short* __restrict__ Wb,
                                              const float* __restrict__ tq,
                                              const float* __restrict__ dq,
                                              const float* __restrict__ bvec,
                                              const float* __restrict__ gamma,
                                              const float* __restrict__ beta,
                                              float* __restrict__ out,
                                              float* __restrict__ pair) {
    __shared__ int msk[N_];
    __shared__ int jls[N_];
    __shared__ float scs[D_], shs[D_];

    int b = blockIdx.y, i = blockIdx.x;
    int tid = threadIdx.x;
    int mi = mask[b * N_ + i];

    f32x4 z4 = (f32x4)(0.f);
    f32x4* outrow = (f32x4*)(out + (size_t)(b * N_ + i) * N_ * D_);

    if (!mi) {
        // ultra-light dead path: no LDS, no barrier, pure streaming
        __builtin_nontemporal_store(0.0f, &pair[(size_t)(b * N_ + i) * N_ + tid]);
#pragma unroll
        for (int p = 0; p < 32; ++p)
            __builtin_nontemporal_store(z4, &outrow[tid + 256 * p]);
        return;
    }

    msk[tid] = mask[b * N_ + tid];
    jls[tid] = jlist[b * N_ + tid];

    if (tid < D_) {
        float cnt = 0.0f;
#pragma unroll
        for (int bb = 0; bb < B_; ++bb) {
            float k = (float)jcnt[bb];
            cnt += k * k - k;
        }
        if (cnt < 1.0f) cnt = 1.0f;
        float be = bvec[tid];
        float mean = dq[tid] / cnt + be;
        float eh2 = tq[tid] / cnt + 2.0f * be * mean - be * be;
        float var = eh2 - mean * mean;
        if (var < 0.0f) var = 0.0f;
        float s = gamma[tid] * rsqrtf(var + 1e-5f);
        scs[tid] = s;
        shs[tid] = be * s + beta[tid] - mean * s;
    }
    __syncthreads();   // the only barrier

    float pm = (msk[tid] && tid != i) ? 1.0f : 0.0f;
    __builtin_nontemporal_store(pm, &pair[(size_t)(b * N_ + i) * N_ + tid]);

    // zero rows not produced below: unmasked j and j == i
    {
        int c = tid & 31, g = tid >> 5;
        for (int j = g; j < N_; j += 8)
            if (!msk[j] || j == i)
                __builtin_nontemporal_store(z4, &outrow[j * 32 + c]);
    }

    int w = tid >> 6, l = tid & 63;
    int lo16 = l & 15, hi4 = l >> 4;
    int E0 = w * 32;

    const float* xi = x + (size_t)(b * N_ + i) * D_;

    // per-lane x_i fragments: ks in 0..3, d = ks*32 + hi4*8 .. +7
    float4 xi0[4], xi1[4];
#pragma unroll
    for (int ks = 0; ks < 4; ++ks) {
        int d = ks * 32 + hi4 * 8;
        xi0[ks] = *(const float4*)(xi + d);
        xi1[ks] = *(const float4*)(xi + d + 4);
    }

    // B fragments (interleaved e-columns): e = E0 + 2*lo16 + et
    bf16x8 bfrag[2][4];
#pragma unroll
    for (int et = 0; et < 2; ++et) {
        int e = E0 + 2 * lo16 + et;
#pragma unroll
        for (int ks = 0; ks < 4; ++ks)
            bfrag[et][ks] = *(const bf16x8*)(Wb + (size_t)e * D_ + ks * 32 + hi4 * 8);
    }

    float sc0 = scs[E0 + 2 * lo16], sh0 = shs[E0 + 2 * lo16];
    float sc1 = scs[E0 + 2 * lo16 + 1], sh1 = shs[E0 + 2 * lo16 + 1];

    int kc = jcnt[b];
    const float* xb = x + (size_t)b * N_ * D_;
    float* outbase = out + (size_t)(b * N_ + i) * N_ * D_;

    for (int jt = 0; jt < kc; jt += 64) {
#pragma unroll
        for (int jq = 0; jq < 4; ++jq) {
            // A row this lane feeds: rA = jq*16 + lo16 (clamped; garbage rows not stored)
            int idx = jt + jq * 16 + lo16;
            int cidx = idx < kc ? idx : kc - 1;
            const float* xj = xb + (size_t)jls[cidx] * D_;

            f32x4 acc0 = (f32x4)(0.f);
            f32x4 acc1 = (f32x4)(0.f);
#pragma unroll
            for (int ks = 0; ks < 4; ++ks) {
                int d = ks * 32 + hi4 * 8;
                float4 a0 = *(const float4*)(xj + d);
                float4 a1 = *(const float4*)(xj + d + 4);
                uint4 pk;
                pk.x = pack2bf(a0.x * xi0[ks].x, a0.y * xi0[ks].y);
                pk.y = pack2bf(a0.z * xi0[ks].z, a0.w * xi0[ks].w);
                pk.z = pack2bf(a1.x * xi1[ks].x, a1.y * xi1[ks].y);
                pk.w = pack2bf(a1.z * xi1[ks].z, a1.w * xi1[ks].w);
                bf16x8 afr = *(bf16x8*)&pk;
                acc0 = __builtin_amdgcn_mfma_f32_16x16x32_bf16(afr, bfrag[0][ks], acc0, 0, 0, 0);
                acc1 = __builtin_amdgcn_mfma_f32_16x16x32_bf16(afr, bfrag[1][ks], acc1, 0, 0, 0);
            }

            // epilogue: D row = hi4*4+v (+jq*16+jt), col = lo16
#pragma unroll
            for (int v = 0; v < 4; ++v) {
                int jrow = jt + jq * 16 + hi4 * 4 + v;
                if (jrow < kc) {
                    int j = jls[jrow];
                    if (j != i) {
                        float h0 = acc0[v] * sc0 + sh0;
                        float h1 = acc1[v] * sc1 + sh1;
                        f32x2 o;
                        o.x = h0 >= 0.f ? h0 : 0.01f * h0;
                        o.y = h1 >= 0.f ? h1 : 0.01f * h1;
                        __builtin_nontemporal_store(o,
                            (f32x2*)(outbase + (size_t)j * D_ + E0 + 2 * lo16));
                    }
                }
            }
        }
    }
}

extern "C" void kernel_launch(void* const* d_in, const int* in_sizes, int n_in,
                              void* d_out, int out_size, void* d_ws, size_t ws_size,
                              hipStream_t stream) {
    const float* x = (const float*)d_in[0];
    const void* edges = d_in[1];
    const void* mask_in = d_in[2];
    const float* W = (const float*)d_in[3];
    const float* bvec = (const float*)d_in[4];
    const float* gamma = (const float*)d_in[5];
    const float* beta = (const float*)d_in[6];

    float* out = (float*)d_out;
    float* pair = out + (size_t)B_ * N_ * N_ * D_;

    char* ws = (char*)d_ws;
    int* mask = (int*)(ws + 0);
    int* jlist = (int*)(ws + 8192);
    int* jcnt = (int*)(ws + 16384);
    float* tq = (float*)(ws + 16448);
    float* dq = (float*)(ws + 16960);
    unsigned short* Wb = (unsigned short*)(ws + 17472);
    float* Wt = (float*)(ws + 50240);
    float* s1 = (float*)(ws + 115776);
    float* cdiag = (float*)(ws + 119872);
    float* part = (float*)(ws + 123968);

    k_prep<<<73, 256, 0, stream>>>(edges, mask_in, W, mask, jlist, jcnt, Wb, Wt, tq, dq);
    {
        dim3 g(D_, B_);
        k_gram3<<<g, 128, 0, stream>>>(x, jlist, jcnt, part, s1, cdiag);
    }
    k_mw2<<<128, 128, 0, stream>>>(part, Wt, s1, cdiag, tq, dq);
    {
        dim3 g(N_, B_);
        k_main<<<g, 256, 0, stream>>>(x, mask, jlist, jcnt, Wb, tq, dq,
                                      bvec, gamma, beta, out, pair);
    }
}

// Round 13
// 94.839 us; speedup vs baseline: 1.1931x; 1.1931x over previous
//
#include <hip/hip_runtime.h>

#define B_ 8
#define N_ 256
#define D_ 128
#define E_ 4096

typedef __attribute__((ext_vector_type(8))) short bf16x8;
typedef __attribute__((ext_vector_type(4))) float f32x4;
typedef __attribute__((ext_vector_type(2))) float f32x2;

__device__ inline unsigned int pack2bf(float lo, float hi) {
    unsigned ul = __float_as_uint(lo);
    ul = ul + 0x7FFFu + ((ul >> 16) & 1u);
    unsigned uh = __float_as_uint(hi);
    uh = uh + 0x7FFFu + ((uh >> 16) & 1u);
    return (ul >> 16) | (uh & 0xFFFF0000u);
}

__device__ inline unsigned short f2bf(float f) {
    unsigned u = __float_as_uint(f);
    u = u + 0x7FFFu + ((u >> 16) & 1u);
    return (unsigned short)(u >> 16);
}

// ---------------- ws layout (bytes) ----------------
// 0      : mask   int32 [B*N]     (8192)
// 8192   : jlist  int32 [B*N]     (8192)
// 16384  : jcnt   int32 [B]       (32)
// 16448  : tq     f32 [D]         (512)
// 16960  : dq     f32 [D]         (512)
// 17472  : Wb     bf16 [E][D]     (32768)
// 50240  : Wt     f32 [D][E]      (65536)
// 115776 : s1     f32 [B][D]      (4096)
// 119872 : cdiag  f32 [B][D]      (4096)
// 123968 : part   f32 [B][D][D]   (524288)

__global__ __launch_bounds__(256) void k_prep(const void* __restrict__ edges_raw,
                                              const void* __restrict__ mask_raw,
                                              const float* __restrict__ W,
                                              int* __restrict__ mask,
                                              int* __restrict__ jlist,
                                              int* __restrict__ jcnt,
                                              unsigned short* __restrict__ Wb,
                                              float* __restrict__ Wt,
                                              float* __restrict__ tq,
                                              float* __restrict__ dq) {
    int blk = blockIdx.x, tid = threadIdx.x;
    if (blk >= B_) {
        int idx = (blk - B_) * 256 + tid;      // 0..16639
        if (idx < 16384) {
            float w = W[idx];
            Wb[idx] = f2bf(w);
            int e = idx >> 7, d = idx & 127;
            Wt[d * D_ + e] = w;
        } else if (idx < 16512) tq[idx - 16384] = 0.0f;
        else dq[idx - 16512] = 0.0f;
        return;
    }
    int b = blk;
    __shared__ unsigned char hit[N_];
    __shared__ int flags[2];
    __shared__ int wcnt[4], wbase[4];
    hit[tid] = 0;
    if (tid < 2) flags[tid] = 0;
    __syncthreads();

    const unsigned char* mb = (const unsigned char*)mask_raw;
    int loc_m = 0;
    for (int idx = tid; idx < B_ * N_; idx += 256)
        if ((idx & 3) && mb[idx]) loc_m = 1;
    if (loc_m) flags[0] = 1;
    const int* e32 = (const int*)edges_raw;
    int loc_e = 0;
    for (int idx = tid; idx < 2 * E_; idx += 256)
        if ((idx & 1) && e32[idx]) loc_e = 1;
    if (loc_e) flags[1] = 1;
    __syncthreads();

    int mask_is_u8 = flags[0], e_is_i32 = flags[1];
    const long long* e64 = (const long long*)edges_raw;
    for (int e = tid; e < E_; e += 256) {
        int s, d;
        if (e_is_i32) { s = e32[e]; d = e32[E_ + e]; }
        else          { s = (int)e64[e]; d = (int)e64[E_ + e]; }
        if (d - s == 3) { hit[s] = 1; hit[d] = 1; }
    }
    __syncthreads();

    const int* m32 = (const int*)mask_raw;
    int lane = tid & 63, wid = tid >> 6;
    int raw = mask_is_u8 ? (int)(mb[b * N_ + tid] != 0) : (int)(m32[b * N_ + tid] != 0);
    int m = raw && (hit[tid] == 0);
    mask[b * N_ + tid] = m;
    unsigned long long bal = __ballot(m);
    if (lane == 0) wcnt[wid] = __popcll(bal);
    __syncthreads();
    if (tid == 0) {
        int base = 0;
        for (int w = 0; w < 4; ++w) { wbase[w] = base; base += wcnt[w]; }
        jcnt[b] = base;
    }
    __syncthreads();
    if (m) {
        int pos = wbase[wid] + __popcll(bal & ((1ull << lane) - 1ull));
        jlist[b * N_ + pos] = tid;
    }
}

__global__ __launch_bounds__(128) void k_gram3(const float* __restrict__ x,
                                               const int* __restrict__ jlist,
                                               const int* __restrict__ jcnt,
                                               float* __restrict__ part,
                                               float* __restrict__ s1,
                                               float* __restrict__ cdiag) {
    int d = blockIdx.x, b = blockIdx.y, dp = threadIdx.x;
    int kc = jcnt[b];
    const int* jl = jlist + b * N_;
    const float* xb = x + (size_t)b * N_ * D_;
    float c0 = 0, c1 = 0, q0 = 0, q1 = 0, s0 = 0, s1a = 0;
    int t = 0;
    for (; t + 1 < kc; t += 2) {
        int i0 = jl[t], i1 = jl[t + 1];
        float xd0 = xb[i0 * D_ + d], xp0 = xb[i0 * D_ + dp];
        float xd1 = xb[i1 * D_ + d], xp1 = xb[i1 * D_ + dp];
        c0 += xd0 * xp0; q0 += (xd0 * xd0) * (xp0 * xp0); s0 += xd0;
        c1 += xd1 * xp1; q1 += (xd1 * xd1) * (xp1 * xp1); s1a += xd1;
    }
    if (t < kc) {
        int i0 = jl[t];
        float xd0 = xb[i0 * D_ + d], xp0 = xb[i0 * D_ + dp];
        c0 += xd0 * xp0; q0 += (xd0 * xd0) * (xp0 * xp0); s0 += xd0;
    }
    float c = c0 + c1, q = q0 + q1, sa = s0 + s1a;
    part[((size_t)b * D_ + d) * D_ + dp] = c * c - q;
    if (dp == d) cdiag[b * D_ + d] = c;
    if (dp == 0) s1[b * D_ + d] = sa;
}

__global__ __launch_bounds__(128) void k_mw2(const float* __restrict__ part,
                                             const float* __restrict__ Wt,
                                             const float* __restrict__ s1,
                                             const float* __restrict__ cdiag,
                                             float* __restrict__ tq,
                                             float* __restrict__ dq) {
    __shared__ float Ms[D_];
    __shared__ float svs;
    int d = blockIdx.x, e = threadIdx.x;
    float m = 0.0f;
#pragma unroll
    for (int b = 0; b < B_; ++b) m += part[((size_t)b * D_ + d) * D_ + e];
    Ms[e] = m;
    if (e == 0) {
        float sv = 0.0f;
#pragma unroll
        for (int b = 0; b < B_; ++b) {
            float s = s1[b * D_ + d];
            sv += s * s - cdiag[b * D_ + d];
        }
        svs = sv;
    }
    __syncthreads();
    float y = 0.0f;
#pragma unroll 8
    for (int p = 0; p < D_; ++p) y += Ms[p] * Wt[p * D_ + e];
    float wed = Wt[d * D_ + e];
    atomicAdd(tq + e, wed * y);
    atomicAdd(dq + e, wed * svs);
}

// Interleaved role-split mega kernel, LDS <= ~11KB so 8 blocks/CU co-reside.
// blk%5==0 -> compute block cblk = blk/5 in [0,2048)
// else     -> zero block zblk = blk - blk/5 - 1 in [0,8192), NO LDS, NO barrier.
__global__ __launch_bounds__(256) void k_mega(const float* __restrict__ x,
                                              const int* __restrict__ mask,
                                              const int* __restrict__ jlist,
                                              const int* __restrict__ jcnt,
                                              const unsigned short* __restrict__ Wb,
                                              const float* __restrict__ tq,
                                              const float* __restrict__ dq,
                                              const float* __restrict__ bvec,
                                              const float* __restrict__ gamma,
                                              const float* __restrict__ beta,
                                              float* __restrict__ out,
                                              float* __restrict__ pair) {
    __shared__ int msk[N_];
    __shared__ int jls[N_];
    __shared__ __align__(16) unsigned char Vsb[32 * 256];   // 32 rows x 128 bf16, swizzled
    __shared__ float scs[D_], shs[D_];

    int blk = blockIdx.x, tid = threadIdx.x;
    int q5 = blk / 5;
    f32x4 z4 = (f32x4)(0.f);

    if (blk != q5 * 5) {
        // ---------------- zero role: no LDS, no barrier ----------------
        int zblk = blk - q5 - 1;
        int r0 = zblk * 64;
        int j0 = r0 & 255;
        int i = (r0 >> 8) & 255;
        int b = r0 >> 16;
        int mi = mask[b * N_ + i];
        f32x4* outrow = (f32x4*)(out + (size_t)(b * N_ + i) * N_ * D_);
        int c = tid & 31, g = tid >> 5;
#pragma unroll
        for (int p = 0; p < 8; ++p) {
            int j = j0 + g + 8 * p;
            int mj = mask[b * N_ + j];
            if (!mi || !mj || j == i)
                __builtin_nontemporal_store(z4, &outrow[(size_t)j * 32 + c]);
        }
        return;
    }

    // ---------------- compute role ----------------
    int cblk = q5;
    int b = cblk >> 8, i = cblk & 255;
    int mi = mask[b * N_ + i];

    if (!mi) {
        // dead: pair row zeros (slab rows handled by zero role); no LDS, no barrier
        __builtin_nontemporal_store(0.0f, &pair[(size_t)(b * N_ + i) * N_ + tid]);
        return;
    }

    msk[tid] = mask[b * N_ + tid];
    jls[tid] = jlist[b * N_ + tid];

    if (tid < D_) {
        float cnt = 0.0f;
#pragma unroll
        for (int bb = 0; bb < B_; ++bb) {
            float k = (float)jcnt[bb];
            cnt += k * k - k;
        }
        if (cnt < 1.0f) cnt = 1.0f;
        float be = bvec[tid];
        float mean = dq[tid] / cnt + be;
        float eh2 = tq[tid] / cnt + 2.0f * be * mean - be * be;
        float var = eh2 - mean * mean;
        if (var < 0.0f) var = 0.0f;
        float s = gamma[tid] * rsqrtf(var + 1e-5f);
        scs[tid] = s;
        shs[tid] = be * s + beta[tid] - mean * s;
    }
    __syncthreads();

    float pm = (msk[tid] && tid != i) ? 1.0f : 0.0f;
    __builtin_nontemporal_store(pm, &pair[(size_t)(b * N_ + i) * N_ + tid]);

    int w = tid >> 6, l = tid & 63;
    int lo16 = l & 15, hi4 = l >> 4;
    int E0 = w * 32;

    // B fragments (interleaved e-columns): e = E0 + 2*lo16 + et
    bf16x8 bfrag[2][4];
#pragma unroll
    for (int et = 0; et < 2; ++et) {
        int e = E0 + 2 * lo16 + et;
#pragma unroll
        for (int ks = 0; ks < 4; ++ks)
            bfrag[et][ks] = *(const bf16x8*)(Wb + (size_t)e * D_ + ks * 32 + hi4 * 8);
    }

    float sc0 = scs[E0 + 2 * lo16], sh0 = shs[E0 + 2 * lo16];
    float sc1 = scs[E0 + 2 * lo16 + 1], sh1 = shs[E0 + 2 * lo16 + 1];

    int kc = jcnt[b];
    const float* xi = x + (size_t)(b * N_ + i) * D_;
    const float* xb = x + (size_t)b * N_ * D_;
    float* outbase = out + (size_t)(b * N_ + i) * N_ * D_;

    for (int jt = 0; jt < kc; jt += 32) {
        __syncthreads();   // Vsb free for restaging
        int jn = kc - jt; if (jn > 32) jn = 32;

        // stage 32 rows: thread r = tid>>3 (0..31), q = tid&7 -> 16 floats d0=q*16
        {
            int r = tid >> 3, q = tid & 7;
            int jrow = jt + r;
            bool ok = (r < jn);
            const float* xj = ok ? (xb + (size_t)jls[jrow] * D_) : xi;
            int d0 = q * 16;
            int rx = (r & 7) << 4;
            float4 a0 = *(const float4*)(xj + d0);
            float4 a1 = *(const float4*)(xj + d0 + 4);
            float4 a2 = *(const float4*)(xj + d0 + 8);
            float4 a3 = *(const float4*)(xj + d0 + 12);
            float4 b0 = *(const float4*)(xi + d0);
            float4 b1 = *(const float4*)(xi + d0 + 4);
            float4 b2 = *(const float4*)(xi + d0 + 8);
            float4 b3 = *(const float4*)(xi + d0 + 12);
            uint4 pk1, pk2;
            pk1.x = pack2bf(a0.x * b0.x, a0.y * b0.y);
            pk1.y = pack2bf(a0.z * b0.z, a0.w * b0.w);
            pk1.z = pack2bf(a1.x * b1.x, a1.y * b1.y);
            pk1.w = pack2bf(a1.z * b1.z, a1.w * b1.w);
            pk2.x = pack2bf(a2.x * b2.x, a2.y * b2.y);
            pk2.y = pack2bf(a2.z * b2.z, a2.w * b2.w);
            pk2.z = pack2bf(a3.x * b3.x, a3.y * b3.y);
            pk2.w = pack2bf(a3.z * b3.z, a3.w * b3.w);
            if (!ok) { pk1 = make_uint4(0, 0, 0, 0); pk2 = pk1; }
            *(uint4*)(Vsb + r * 256 + ((2 * d0) ^ rx)) = pk1;
            *(uint4*)(Vsb + r * 256 + ((2 * (d0 + 8)) ^ rx)) = pk2;
        }
        __syncthreads();

        // MFMA: per wave, 2 j-subtiles x 2 e-subtiles x 4 k-steps
#pragma unroll
        for (int jq = 0; jq < 2; ++jq) {
            f32x4 acc0 = (f32x4)(0.f);
            f32x4 acc1 = (f32x4)(0.f);
            int rA = jq * 16 + lo16;
            int rbase = rA * 256;
            int rx = (rA & 7) << 4;
#pragma unroll
            for (int ks = 0; ks < 4; ++ks) {
                bf16x8 afr = *(const bf16x8*)(Vsb + rbase + ((ks * 64 + hi4 * 16) ^ rx));
                acc0 = __builtin_amdgcn_mfma_f32_16x16x32_bf16(afr, bfrag[0][ks], acc0, 0, 0, 0);
                acc1 = __builtin_amdgcn_mfma_f32_16x16x32_bf16(afr, bfrag[1][ks], acc1, 0, 0, 0);
            }
#pragma unroll
            for (int v = 0; v < 4; ++v) {
                int jrow = jt + jq * 16 + hi4 * 4 + v;
                if (jrow < kc) {
                    int j = jls[jrow];
                    if (j != i) {
                        float h0 = acc0[v] * sc0 + sh0;
                        float h1 = acc1[v] * sc1 + sh1;
                        f32x2 o;
                        o.x = h0 >= 0.f ? h0 : 0.01f * h0;
                        o.y = h1 >= 0.f ? h1 : 0.01f * h1;
                        __builtin_nontemporal_store(o,
                            (f32x2*)(outbase + (size_t)j * D_ + E0 + 2 * lo16));
                    }
                }
            }
        }
    }
}

extern "C" void kernel_launch(void* const* d_in, const int* in_sizes, int n_in,
                              void* d_out, int out_size, void* d_ws, size_t ws_size,
                              hipStream_t stream) {
    const float* x = (const float*)d_in[0];
    const void* edges = d_in[1];
    const void* mask_in = d_in[2];
    const float* W = (const float*)d_in[3];
    const float* bvec = (const float*)d_in[4];
    const float* gamma = (const float*)d_in[5];
    const float* beta = (const float*)d_in[6];

    float* out = (float*)d_out;
    float* pair = out + (size_t)B_ * N_ * N_ * D_;

    char* ws = (char*)d_ws;
    int* mask = (int*)(ws + 0);
    int* jlist = (int*)(ws + 8192);
    int* jcnt = (int*)(ws + 16384);
    float* tq = (float*)(ws + 16448);
    float* dq = (float*)(ws + 16960);
    unsigned short* Wb = (unsigned short*)(ws + 17472);
    float* Wt = (float*)(ws + 50240);
    float* s1 = (float*)(ws + 115776);
    float* cdiag = (float*)(ws + 119872);
    float* part = (float*)(ws + 123968);

    k_prep<<<73, 256, 0, stream>>>(edges, mask_in, W, mask, jlist, jcnt, Wb, Wt, tq, dq);
    {
        dim3 g(D_, B_);
        k_gram3<<<g, 128, 0, stream>>>(x, jlist, jcnt, part, s1, cdiag);
    }
    k_mw2<<<128, 128, 0, stream>>>(part, Wt, s1, cdiag, tq, dq);
    k_mega<<<10240, 256, 0, stream>>>(x, mask, jlist, jcnt, Wb, tq, dq,
                                      bvec, gamma, beta, out, pair);
}